// Round 6
// baseline (388.244 us; speedup 1.0000x reference)
//
#include <hip/hip_runtime.h>
#include <hip/hip_bf16.h>

// Problem constants (B=32, N=256, K=20, channels 3->64->128->256, fc 256->128->40)
#define B_ 32
#define N_ 256
#define K_ 20
#define C1 64
#define C2 128
#define C3 256
#define F1 128
#define F2 40
#define NBLK 512
#define NEG_INF (-3.402823466e38f)

// ---------------------------------------------------------------------------
// Single persistent kernel, 512 blocks x 256 threads, 3 phases split by
// grid-wide flag barriers (all blocks co-resident: 45.6 KB LDS -> >=2
// blocks/CU guaranteed, 512 <= 2x256).
//   Phase 1: weight fold/transpose prep (grid-strided) + per-point top-20
//            (16 points/block, one wave-point at a time, barrier-free argmax).
//   Phase 2: per-point MLP 3->64->128->256 (16 points/block; coalesced
//            transposed-weight streams + LDS-broadcast activations).
//   Phase 3: fused gather-max + fc1(relu) + fc2 (one (b,16ch) unit per block).
// Barrier: flags[i] = phase, agent-scope release; thread t polls flags[t],
// flags[t+256] with acquire. Initial flag value is the 0xAA poison
// (negative as int) or fresh zeros -- both < 1, so phases {1,2} are safe.
// ---------------------------------------------------------------------------
__global__ __launch_bounds__(256) void k_all(const float* __restrict__ x,
    const float* __restrict__ w1, const float* __restrict__ s1, const float* __restrict__ b1,
    const float* __restrict__ w2, const float* __restrict__ s2, const float* __restrict__ b2,
    const float* __restrict__ w3, const float* __restrict__ s3, const float* __restrict__ b3,
    const float* __restrict__ fc1w, const float* __restrict__ fc1b,
    const float* __restrict__ fc2w, const float* __restrict__ fc2b,
    int* __restrict__ flags, int* __restrict__ idx, float* __restrict__ P,
    float* __restrict__ w1f, float* __restrict__ w2T, float* __restrict__ w3T,
    float* __restrict__ fc1T, float* __restrict__ out) {

    __shared__ float smem[11392];       // 45.6 KB union across phases
    const int blk  = blockIdx.x;
    const int t    = threadIdx.x;
    const int lane = t & 63;
    const int wv   = t >> 6;

    // ================= PHASE 1: prep + top-20 =================
    {
        // ---- weight prep, one element per thread (73920 total < 131072) ----
        const int g = blk * 256 + t;
        if (g < 192) {
            w1f[g] = w1[g] * s1[g / 3];
        } else if (g < 8384) {
            const int e = g - 192;   const int oc = e >> 6, k = e & 63;
            w2T[k * C2 + oc] = w2[e] * s2[oc];
        } else if (g < 41152) {
            const int e = g - 8384;  const int oc = e >> 7, k = e & 127;
            w3T[k * C3 + oc] = w3[e] * s3[oc];
        } else if (g < 73920) {
            const int e = g - 41152; const int j = e >> 8, n = e & 255;
            fc1T[n * F1 + j] = fc1w[e];
        }

        // ---- top-20: block = (b, 16-point slab); wave does 4 points ----
        float* xs  = smem;              // 768
        float* xxs = smem + 768;        // 256
        const int b  = blk >> 4;
        const int n0 = (blk & 15) * 16;

        const float* xb = x + (size_t)b * N_ * 3;
        for (int e = t; e < N_ * 3; e += 256) xs[e] = xb[e];
        __syncthreads();
        {
            const float a0 = xs[t * 3 + 0], a1 = xs[t * 3 + 1], a2 = xs[t * 3 + 2];
            xxs[t] = a0 * a0 + a1 * a1 + a2 * a2;
        }
        __syncthreads();

        for (int pi = 0; pi < 4; ++pi) {
            const int n  = n0 + (wv << 2) + pi;
            const int bn = (b << 8) | n;
            const float nx = xs[n * 3 + 0], ny = xs[n * 3 + 1], nz = xs[n * 3 + 2];
            const float xxn = xxs[n];

            unsigned long long k0, k1, k2, k3;
            {
                unsigned long long kk[4];
                #pragma unroll
                for (int i = 0; i < 4; ++i) {
                    const int m = lane + (i << 6);
                    const float cx = xs[m * 3 + 0], cy = xs[m * 3 + 1], cz = xs[m * 3 + 2];
                    const float v = 2.0f * (nx * cx + ny * cy + nz * cz) - xxn - xxs[m];
                    unsigned u = __float_as_uint(v);
                    unsigned key32 = (u & 0x80000000u) ? ~u : (u | 0x80000000u);
                    kk[i] = ((unsigned long long)key32 << 8) | (unsigned)(255 - m);
                }
                k0 = kk[0]; k1 = kk[1]; k2 = kk[2]; k3 = kk[3];
            }

            int mine = 0;
            #pragma unroll 1
            for (int it = 0; it < K_; ++it) {
                unsigned long long ra = (k0 > k1) ? k0 : k1;
                unsigned long long rb = (k2 > k3) ? k2 : k3;
                unsigned long long rk = (ra > rb) ? ra : rb;
                #pragma unroll
                for (int s = 1; s < 64; s <<= 1) {
                    unsigned long long ok = __shfl_xor(rk, s, 64);
                    if (ok > rk) rk = ok;
                }
                const int ri = 255 - (int)(rk & 0xFFull);
                if (lane == it) mine = ri;
                if (lane == (ri & 63)) {
                    const int slot = ri >> 6;
                    if      (slot == 0) k0 = 0ull;
                    else if (slot == 1) k1 = 0ull;
                    else if (slot == 2) k2 = 0ull;
                    else                k3 = 0ull;
                }
            }
            if (lane < K_) idx[(size_t)bn * K_ + lane] = mine;
        }
    }

    // ================= BARRIER 1 =================
    __syncthreads();
    __threadfence();
    if (t == 0)
        __hip_atomic_store(&flags[blk], 1, __ATOMIC_RELEASE, __HIP_MEMORY_SCOPE_AGENT);
    for (int f = t; f < NBLK; f += 256)
        while (__hip_atomic_load(&flags[f], __ATOMIC_ACQUIRE, __HIP_MEMORY_SCOPE_AGENT) < 1)
            __builtin_amdgcn_s_sleep(1);
    __syncthreads();
    __threadfence();

    // ================= PHASE 2: per-point MLP, 16 pts/block =================
    {
        float* xs2 = smem;              // 48
        float* y1  = smem + 64;         // 64 x 16 = 1024
        float* y2  = smem + 1088;       // 128 x 16 = 2048
        const int pbase = blk * 16;
        const int p0 = wv * 4;          // wave's 4-point quad

        if (t < 48) xs2[t] = x[(size_t)pbase * 3 + t];
        __syncthreads();

        // ---- layer 1: 64 x 3; thread = (oc, pt-quad) ----
        {
            const int oc = t & 63;
            const float wa = w1f[oc * 3 + 0], wb = w1f[oc * 3 + 1], wc = w1f[oc * 3 + 2];
            const float bb = b1[oc];
            float4 v;
            #pragma unroll
            for (int p = 0; p < 4; ++p) {
                const int pp = p0 + p;
                (&v.x)[p] = fmaxf(wa * xs2[pp * 3 + 0] + wb * xs2[pp * 3 + 1]
                                  + wc * xs2[pp * 3 + 2] + bb, 0.0f);
            }
            *(float4*)&y1[oc * 16 + p0] = v;
        }
        __syncthreads();

        // ---- layer 2: 128oc x 64k; lane owns oc-pair, wave owns pt-quad ----
        {
            float acc[2][4] = {};
            #pragma unroll 4
            for (int k = 0; k < C1; ++k) {
                const float2 w = *(const float2*)&w2T[k * C2 + lane * 2];   // coalesced
                const float4 a = *(const float4*)&y1[k * 16 + p0];          // broadcast
                #pragma unroll
                for (int p = 0; p < 4; ++p) {
                    acc[0][p] += w.x * (&a.x)[p];
                    acc[1][p] += w.y * (&a.x)[p];
                }
            }
            #pragma unroll
            for (int o = 0; o < 2; ++o) {
                const int oc = lane * 2 + o;
                const float bb = b2[oc];
                float4 v;
                #pragma unroll
                for (int p = 0; p < 4; ++p) (&v.x)[p] = fmaxf(acc[o][p] + bb, 0.0f);
                *(float4*)&y2[oc * 16 + p0] = v;
            }
        }
        __syncthreads();

        // ---- layer 3: 256oc x 128k; lane owns oc-quad, wave owns pt-quad ----
        {
            float acc[4][4] = {};
            #pragma unroll 4
            for (int k = 0; k < C2; ++k) {
                const float4 w = *(const float4*)&w3T[k * C3 + lane * 4];   // coalesced 1KB
                const float4 a = *(const float4*)&y2[k * 16 + p0];          // broadcast
                #pragma unroll
                for (int o = 0; o < 4; ++o) {
                    const float wv_ = (&w.x)[o];
                    #pragma unroll
                    for (int p = 0; p < 4; ++p) acc[o][p] += wv_ * (&a.x)[p];
                }
            }
            const float4 bb = *(const float4*)&b3[lane * 4];
            #pragma unroll
            for (int p = 0; p < 4; ++p) {
                float4 v;
                #pragma unroll
                for (int o = 0; o < 4; ++o)
                    (&v.x)[o] = fmaxf(acc[o][p] + (&bb.x)[o], 0.0f);
                *(float4*)&P[(size_t)(pbase + p0 + p) * C3 + lane * 4] = v;  // coalesced
            }
        }
    }

    // ================= BARRIER 2 =================
    __syncthreads();
    __threadfence();
    if (t == 0)
        __hip_atomic_store(&flags[blk], 2, __ATOMIC_RELEASE, __HIP_MEMORY_SCOPE_AGENT);
    for (int f = t; f < NBLK; f += 256)
        while (__hip_atomic_load(&flags[f], __ATOMIC_ACQUIRE, __HIP_MEMORY_SCOPE_AGENT) < 2)
            __builtin_amdgcn_s_sleep(1);
    __syncthreads();
    __threadfence();

    // ================= PHASE 3: gather-max + fc1 + fc2 =================
    {
        float* Ht  = smem;              // [n][ci] 256x16 = 4096
        float* gl  = smem + 4096;       // [ci][j] 16x132 = 2112 (padded)
        float* w2l = smem + 6208;       // [m][j]  40x129 = 5160 (padded)
        const int b   = blk >> 4;
        const int ch0 = (blk & 15) * 16;

        for (int e = t; e < F2 * F1; e += 256)
            w2l[(e >> 7) * 129 + (e & 127)] = fc2w[e];

        // ---- stage A: gather-max into Ht ----
        {
            const int q  = t & 3;       // ch-quad
            const int nl = t >> 2;      // n within quarter-pass
            const float* Pq = P + (size_t)b * N_ * C3 + ch0 + q * 4;
            #pragma unroll
            for (int r = 0; r < 4; ++r) {
                const int n = r * 64 + nl;
                const int* ib = idx + ((size_t)((b << 8) | n)) * K_;
                float4 m = make_float4(NEG_INF, NEG_INF, NEG_INF, NEG_INF);
                #pragma unroll
                for (int j = 0; j < K_; ++j) {
                    const int id = ib[j];
                    const float4 p = *(const float4*)(Pq + (size_t)id * C3);
                    m.x = fmaxf(m.x, p.x);
                    m.y = fmaxf(m.y, p.y);
                    m.z = fmaxf(m.z, p.z);
                    m.w = fmaxf(m.w, p.w);
                }
                *(float4*)&Ht[n * 16 + q * 4] = m;
            }
        }
        __syncthreads();

        // ---- stage B: fc1 + relu -> gl[ci][j] ----
        {
            const int c0 = wv * 4;      // wave's ch-quad
            float acc[2][4] = {};
            #pragma unroll 4
            for (int n = 0; n < N_; ++n) {
                const float2 w = *(const float2*)&fc1T[n * F1 + lane * 2];  // coalesced
                const float4 a = *(const float4*)&Ht[n * 16 + c0];          // broadcast
                #pragma unroll
                for (int c = 0; c < 4; ++c) {
                    acc[0][c] += w.x * (&a.x)[c];
                    acc[1][c] += w.y * (&a.x)[c];
                }
            }
            const float bb0 = fc1b[lane * 2], bb1 = fc1b[lane * 2 + 1];
            #pragma unroll
            for (int c = 0; c < 4; ++c) {
                float2 v;
                v.x = fmaxf(acc[0][c] + bb0, 0.0f);
                v.y = fmaxf(acc[1][c] + bb1, 0.0f);
                *(float2*)&gl[(c0 + c) * 132 + lane * 2] = v;
            }
        }
        __syncthreads();

        // ---- stage C: fc2 -> out ----
        for (int o = t; o < 16 * F2; o += 256) {
            const int ci = o / F2;
            const int m  = o % F2;
            float acc = fc2b[m];
            const float* wr = w2l + m * 129;
            const float* gr = gl + ci * 132;
            #pragma unroll 4
            for (int j = 0; j < F1; ++j)
                acc += wr[j] * gr[j];
            out[((size_t)(b * C3 + ch0 + ci)) * F2 + m] = acc;
        }
    }
}

// ---------------------------------------------------------------------------
extern "C" void kernel_launch(void* const* d_in, const int* in_sizes, int n_in,
                              void* d_out, int out_size, void* d_ws, size_t ws_size,
                              hipStream_t stream) {
    const float* x    = (const float*)d_in[0];
    const float* w1   = (const float*)d_in[1];
    const float* s1   = (const float*)d_in[2];
    const float* t1   = (const float*)d_in[3];
    const float* w2   = (const float*)d_in[4];
    const float* s2   = (const float*)d_in[5];
    const float* t2   = (const float*)d_in[6];
    const float* w3   = (const float*)d_in[7];
    const float* s3   = (const float*)d_in[8];
    const float* t3   = (const float*)d_in[9];
    const float* fc1w = (const float*)d_in[10];
    const float* fc1b = (const float*)d_in[11];
    const float* fc2w = (const float*)d_in[12];
    const float* fc2b = (const float*)d_in[13];
    float* out = (float*)d_out;

    // Workspace layout (poisoned 0xAA each call; flags exploit poison < 1):
    char* ws = (char*)d_ws;
    int*   flags = (int*)ws;                                  // 512 ints, 2 KB
    int*   idx   = (int*)(ws + 2048);                         // 655,360 B
    float* P     = (float*)(ws + 2048 + (size_t)B_ * N_ * K_ * 4);  // 8 MB (16B-aligned)
    float* w1f   = P + (size_t)B_ * N_ * C3;                  // 192 f
    float* w2T   = w1f + 256;                                 // 8192 f
    float* w3T   = w2T + C1 * C2;                             // 32768 f
    float* fc1T  = w3T + C2 * C3;                             // 32768 f

    k_all<<<NBLK, 256, 0, stream>>>(x, w1, s1, t1, w2, s2, t2, w3, s3, t3,
                                    fc1w, fc1b, fc2w, fc2b,
                                    flags, idx, P, w1f, w2T, w3T, fc1T, out);
}

// Round 7
// 152.483 us; speedup vs baseline: 2.5462x; 2.5462x over previous
//
#include <hip/hip_runtime.h>
#include <hip/hip_bf16.h>

// Problem constants (B=32, N=256, K=20, channels 3->64->128->256, fc 256->128->40)
#define B_ 32
#define N_ 256
#define K_ 20
#define C1 64
#define C2 128
#define C3 256
#define F1 128
#define F2 40
#define NEG_INF (-3.402823466e38f)

// ---------------------------------------------------------------------------
// NODE 1: three independent block families in one launch (no cross-family
// dependency, so no barrier needed):
//   blocks [0,512):     per-point MLP 3->64->128->256 (16 pts/block, raw
//                       weights w2/w3 streamed per-lane from L1, BN scale
//                       applied at epilogue -- needs NO weight prep).
//   blocks [512,2560):  per-point top-20 (one wave per point, barrier-free
//                       iterative argmax on packed u64 keys).
//   blocks [2560,2576): fc1 weight transpose fc1T[n][j] = fc1w[j][n]
//                       (consumed only by node 2).
// MLP blocks first so the long pole starts immediately.
// LDS union = 12.5 KB -> 12 blocks/CU for every family.
// ---------------------------------------------------------------------------
__global__ __launch_bounds__(256) void k_front(const float* __restrict__ x,
    const float* __restrict__ w1, const float* __restrict__ s1, const float* __restrict__ b1,
    const float* __restrict__ w2, const float* __restrict__ s2, const float* __restrict__ b2,
    const float* __restrict__ w3, const float* __restrict__ s3, const float* __restrict__ b3,
    const float* __restrict__ fc1w,
    int* __restrict__ idx, float* __restrict__ P, float* __restrict__ fc1T) {

    __shared__ float smem[3136];        // union: mlp 3120 f | topk 1024 f
    const int blk = blockIdx.x;
    const int t   = threadIdx.x;

    if (blk < 512) {
        // ================== per-point MLP, 16 points/block ==================
        float* xs  = smem;              // 48
        float* y1t = smem + 64;         // [c1][p] 64x16
        float* y2t = smem + 1088;       // [c2][p] 128x16
        const int pbase = blk * 16;

        if (t < 48) xs[t] = x[(size_t)pbase * 3 + t];
        __syncthreads();

        // ---- layer 1: 64 x 3; thread = (oc, 4-pt quarter) ----
        {
            const int o = t & 63;
            const int q = t >> 6;
            const float wa = w1[o * 3 + 0], wb = w1[o * 3 + 1], wc = w1[o * 3 + 2];
            const float sc = s1[o], sh = b1[o];
            #pragma unroll
            for (int i = 0; i < 4; ++i) {
                const int p = q * 4 + i;
                float vv = wa * xs[p * 3 + 0] + wb * xs[p * 3 + 1] + wc * xs[p * 3 + 2];
                y1t[o * 16 + p] = fmaxf(vv * sc + sh, 0.0f);
            }
        }
        __syncthreads();

        // ---- layer 2: 128 x 64; thread = (oc, 8-pt half) ----
        {
            const int o = t & 127;
            const int h = (t >> 7) * 8;
            float acc[8] = {0, 0, 0, 0, 0, 0, 0, 0};
            const float4* wrow = (const float4*)(w2 + (size_t)o * C1);
            for (int c = 0; c < C1; c += 4) {
                float4 w4 = wrow[c >> 2];
                #pragma unroll
                for (int cc = 0; cc < 4; ++cc) {
                    const float wcc = (&w4.x)[cc];
                    const float* yp = y1t + (c + cc) * 16 + h;
                    #pragma unroll
                    for (int p = 0; p < 8; ++p) acc[p] += wcc * yp[p];
                }
            }
            const float sc = s2[o], sh = b2[o];
            #pragma unroll
            for (int p = 0; p < 8; ++p)
                y2t[o * 16 + h + p] = fmaxf(acc[p] * sc + sh, 0.0f);
        }
        __syncthreads();

        // ---- layer 3: 256 x 128; thread = oc, all 16 pts ----
        {
            const int o = t;
            float acc[16];
            #pragma unroll
            for (int p = 0; p < 16; ++p) acc[p] = 0.0f;
            const float4* wrow = (const float4*)(w3 + (size_t)o * C2);
            for (int c = 0; c < C2; c += 4) {
                float4 w4 = wrow[c >> 2];
                #pragma unroll
                for (int cc = 0; cc < 4; ++cc) {
                    const float wcc = (&w4.x)[cc];
                    const float* yp = y2t + (c + cc) * 16;
                    #pragma unroll
                    for (int p = 0; p < 16; ++p) acc[p] += wcc * yp[p];
                }
            }
            const float sc = s3[o], sh = b3[o];
            #pragma unroll
            for (int p = 0; p < 16; ++p) {
                float vv = fmaxf(acc[p] * sc + sh, 0.0f);
                P[(size_t)(pbase + p) * C3 + o] = vv;   // coalesced per p
            }
        }

    } else if (blk < 2560) {
        // ================== top-20, one wave per point ==================
        float* xs  = smem;              // 768
        float* xxs = smem + 768;        // 256
        const int tb   = blk - 512;
        const int lane = t & 63;
        const int wave = t >> 6;
        const int b    = tb >> 6;
        const int n    = ((tb & 63) << 2) | wave;
        const int bn   = (b << 8) | n;

        const float* xb = x + (size_t)b * N_ * 3;
        for (int e = t; e < N_ * 3; e += 256) xs[e] = xb[e];
        __syncthreads();
        {
            const float a0 = xs[t * 3 + 0], a1 = xs[t * 3 + 1], a2 = xs[t * 3 + 2];
            xxs[t] = a0 * a0 + a1 * a1 + a2 * a2;
        }
        __syncthreads();

        const float nx = xs[n * 3 + 0], ny = xs[n * 3 + 1], nz = xs[n * 3 + 2];
        const float xxn = xxs[n];

        unsigned long long k0, k1, k2, k3;
        {
            unsigned long long kk[4];
            #pragma unroll
            for (int i = 0; i < 4; ++i) {
                const int m = lane + (i << 6);
                const float cx = xs[m * 3 + 0], cy = xs[m * 3 + 1], cz = xs[m * 3 + 2];
                const float v = 2.0f * (nx * cx + ny * cy + nz * cz) - xxn - xxs[m];
                unsigned u = __float_as_uint(v);
                unsigned key32 = (u & 0x80000000u) ? ~u : (u | 0x80000000u);
                kk[i] = ((unsigned long long)key32 << 8) | (unsigned)(255 - m);
            }
            k0 = kk[0]; k1 = kk[1]; k2 = kk[2]; k3 = kk[3];
        }

        int mine = 0;
        #pragma unroll 1
        for (int it = 0; it < K_; ++it) {
            unsigned long long ra = (k0 > k1) ? k0 : k1;
            unsigned long long rb = (k2 > k3) ? k2 : k3;
            unsigned long long rk = (ra > rb) ? ra : rb;
            #pragma unroll
            for (int s = 1; s < 64; s <<= 1) {
                unsigned long long ok = __shfl_xor(rk, s, 64);
                if (ok > rk) rk = ok;
            }
            const int ri = 255 - (int)(rk & 0xFFull);
            if (lane == it) mine = ri;
            if (lane == (ri & 63)) {
                const int slot = ri >> 6;
                if      (slot == 0) k0 = 0ull;
                else if (slot == 1) k1 = 0ull;
                else if (slot == 2) k2 = 0ull;
                else                k3 = 0ull;
            }
        }
        if (lane < K_) idx[(size_t)bn * K_ + lane] = mine;

    } else {
        // ================== fc1 weight transpose ==================
        const int g = (blk - 2560) * 256 + t;   // 0..4095
        #pragma unroll
        for (int i = 0; i < 8; ++i) {           // 32768 elems
            const int e = g + i * 4096;
            const int j = e >> 8, n = e & 255;
            fc1T[n * F1 + j] = fc1w[e];
        }
    }
}

// ---------------------------------------------------------------------------
// NODE 2: FUSED gather-max + fc1(relu) + fc2 (verbatim from R5).
// 512 blocks = (b, 16-ch tile) x 256 threads.
// ---------------------------------------------------------------------------
__global__ __launch_bounds__(256) void k_gfc(const float* __restrict__ P,
                                             const int* __restrict__ idx,
                                             const float* __restrict__ fc1T,
                                             const float* __restrict__ fc1b,
                                             const float* __restrict__ fc2w,
                                             const float* __restrict__ fc2b,
                                             float* __restrict__ out) {
    const int b    = blockIdx.x >> 4;
    const int ch0  = (blockIdx.x & 15) * 16;
    const int t    = threadIdx.x;
    const int lane = t & 63;

    __shared__ float Ht[N_ * 16];       // [n][ci], 16 KB
    __shared__ float gl[16 * 132];      // [ci][j], padded stride 132
    __shared__ float w2l[F2 * 129];     // [m][j], padded (129 = 1 mod 32)

    for (int e = t; e < F2 * F1; e += 256)
        w2l[(e >> 7) * 129 + (e & 127)] = fc2w[e];

    // ---- stage A: gather-max into Ht ----
    {
        const int q  = t & 3;           // ch-quad
        const int nl = t >> 2;          // n within quarter-pass
        const float* Pq = P + (size_t)b * N_ * C3 + ch0 + q * 4;
        #pragma unroll
        for (int r = 0; r < 4; ++r) {
            const int n = r * 64 + nl;
            const int* ib = idx + ((size_t)((b << 8) | n)) * K_;
            float4 m = make_float4(NEG_INF, NEG_INF, NEG_INF, NEG_INF);
            #pragma unroll
            for (int j = 0; j < K_; ++j) {
                const int id = ib[j];
                const float4 p = *(const float4*)(Pq + (size_t)id * C3);
                m.x = fmaxf(m.x, p.x);
                m.y = fmaxf(m.y, p.y);
                m.z = fmaxf(m.z, p.z);
                m.w = fmaxf(m.w, p.w);
            }
            *(float4*)&Ht[n * 16 + q * 4] = m;
        }
    }
    __syncthreads();

    // ---- stage B: fc1 + relu -> gl[ci][j] ----
    {
        const int c0 = (t >> 6) * 4;    // wave's ch-quad
        float acc[2][4] = {};
        #pragma unroll 4
        for (int n = 0; n < N_; ++n) {
            const float2 w = *(const float2*)&fc1T[n * F1 + lane * 2];  // coalesced
            const float4 a = *(const float4*)&Ht[n * 16 + c0];          // broadcast
            #pragma unroll
            for (int c = 0; c < 4; ++c) {
                acc[0][c] += w.x * (&a.x)[c];
                acc[1][c] += w.y * (&a.x)[c];
            }
        }
        const float bb0 = fc1b[lane * 2], bb1 = fc1b[lane * 2 + 1];
        #pragma unroll
        for (int c = 0; c < 4; ++c) {
            float2 v;
            v.x = fmaxf(acc[0][c] + bb0, 0.0f);
            v.y = fmaxf(acc[1][c] + bb1, 0.0f);
            *(float2*)&gl[(c0 + c) * 132 + lane * 2] = v;
        }
    }
    __syncthreads();

    // ---- stage C: fc2 -> out ----
    for (int o = t; o < 16 * F2; o += 256) {
        const int ci = o / F2;
        const int m  = o % F2;
        float acc = fc2b[m];
        const float* wr = w2l + m * 129;
        const float* gr = gl + ci * 132;
        #pragma unroll 4
        for (int j = 0; j < F1; ++j)
            acc += wr[j] * gr[j];
        out[((size_t)(b * C3 + ch0 + ci)) * F2 + m] = acc;
    }
}

// ---------------------------------------------------------------------------
extern "C" void kernel_launch(void* const* d_in, const int* in_sizes, int n_in,
                              void* d_out, int out_size, void* d_ws, size_t ws_size,
                              hipStream_t stream) {
    const float* x    = (const float*)d_in[0];
    const float* w1   = (const float*)d_in[1];
    const float* s1   = (const float*)d_in[2];
    const float* t1   = (const float*)d_in[3];
    const float* w2   = (const float*)d_in[4];
    const float* s2   = (const float*)d_in[5];
    const float* t2   = (const float*)d_in[6];
    const float* w3   = (const float*)d_in[7];
    const float* s3   = (const float*)d_in[8];
    const float* t3   = (const float*)d_in[9];
    const float* fc1w = (const float*)d_in[10];
    const float* fc1b = (const float*)d_in[11];
    const float* fc2w = (const float*)d_in[12];
    const float* fc2b = (const float*)d_in[13];
    float* out = (float*)d_out;

    // Workspace layout (all fully overwritten every call):
    char* ws = (char*)d_ws;
    int*   idx  = (int*)ws;                                  // 655,360 B
    float* P    = (float*)(ws + (size_t)B_ * N_ * K_ * 4);   // 8 MB
    float* fc1T = P + (size_t)B_ * N_ * C3;                  // 131,072 B

    k_front<<<2576, 256, 0, stream>>>(x, w1, s1, t1, w2, s2, t2, w3, s3, t3,
                                      fc1w, idx, P, fc1T);
    k_gfc<<<B_ * 16, 256, 0, stream>>>(P, idx, fc1T, fc1b, fc2w, fc2b, out);
}